// Round 11
// baseline (279.130 us; speedup 1.0000x reference)
//
#include <hip/hip_runtime.h>

#define B 128
#define N 512
#define D 256
#define S 8

typedef float f32x4 __attribute__((ext_vector_type(4)));

__device__ __forceinline__ f32x4 ntload(const f32x4* p) {
    return __builtin_nontemporal_load(p);
}

// ---------------------------------------------------------------------------
// K1 (fused): grid (16, B), block 128 (R3 topology = best measured 63.2us).
//   role in [0,8):  edge chunk -> em[b,:] += sum_i edge[b,i,:]*ka[b,i]
//                   (NT loads: edge is read-once; keep node L3-resident for kD)
//   role in [8,16): node chunk -> kf[b,:] += sum_n node[b,n,:]*ka[b,n]
//                                 + out_att chunk (+ out_sp once)
//   LAST finishing block per b (atomic counter == 15) computes
//   q[b] = W*kf[b] + bias inline  -> kC kernel + one graph boundary removed.
// R10 lesson: asm-forced 16-deep MLP changed nothing -> latency exonerated;
// remaining slack is graph structure + L3 retention.
// ---------------------------------------------------------------------------
__global__ __launch_bounds__(128) void k1_fused(
    const float* __restrict__ node, const float* __restrict__ edge,
    const float* __restrict__ att, const float* __restrict__ spi,
    const float* __restrict__ Wm, const float* __restrict__ bias,
    float* __restrict__ out_att, float* __restrict__ out_sp,
    float* __restrict__ kf, float* __restrict__ em,
    float* __restrict__ q, int* __restrict__ cnt) {
    const int b = blockIdx.y;
    const int role = blockIdx.x;
    const int tid = threadIdx.x;
    __shared__ float sps[S];
    __shared__ float kal[64];
    __shared__ f32x4 red[64];
    __shared__ int lastFlag;
    if (tid < S) sps[tid] = spi[b * S + tid];
    __syncthreads();

    if (role < 8) {
        // ---- edge chunk: 64 rows x 512 cols; thread owns float4-col c ----
        const int i0 = role * 64;
        if (tid < 64) {
            const float4* a = reinterpret_cast<const float4*>(att + ((size_t)(b * N + i0 + tid)) * S);
            float4 a0 = a[0], a1 = a[1];
            kal[tid] = a0.x * sps[0] + a0.y * sps[1] + a0.z * sps[2] + a0.w * sps[3]
                     + a1.x * sps[4] + a1.y * sps[5] + a1.z * sps[6] + a1.w * sps[7];
        }
        __syncthreads();
        const int c = tid;               // float4 column 0..127
        const f32x4* base = reinterpret_cast<const f32x4*>(edge + ((size_t)b * N + i0) * N) + c;
        f32x4 acc = {0.f, 0.f, 0.f, 0.f};
        f32x4 v[16];
        for (int ii = 0; ii < 64; ii += 16) {
            #pragma unroll
            for (int u = 0; u < 16; ++u) v[u] = ntload(base + (size_t)(ii + u) * (N / 4));
            #pragma unroll
            for (int u = 0; u < 16; ++u) acc += kal[ii + u] * v[u];
        }
        float* dst = em + b * N + c * 4;
        unsafeAtomicAdd(dst + 0, acc.x);
        unsafeAtomicAdd(dst + 1, acc.y);
        unsafeAtomicAdd(dst + 2, acc.z);
        unsafeAtomicAdd(dst + 3, acc.w);
    } else {
        // ---- node chunk: 64 rows x 256 cols (+ stack outputs) ----
        const int n0 = (role - 8) * 64;
        if (tid < 64) {
            const float4* a = reinterpret_cast<const float4*>(att + ((size_t)(b * N + n0 + tid)) * S);
            float4 a0 = a[0], a1 = a[1];
            kal[tid] = a0.x * sps[0] + a0.y * sps[1] + a0.z * sps[2] + a0.w * sps[3]
                     + a1.x * sps[4] + a1.y * sps[5] + a1.z * sps[6] + a1.w * sps[7];
            float4 o0 = make_float4(a0.x * (1.f - sps[0]), a0.y * (1.f - sps[1]),
                                    a0.z * (1.f - sps[2]), a0.w * (1.f - sps[3]));
            float4 o1 = make_float4(a1.x * (1.f - sps[4]), a1.y * (1.f - sps[5]),
                                    a1.z * (1.f - sps[6]), a1.w * (1.f - sps[7]));
            float4* oa = reinterpret_cast<float4*>(out_att + ((size_t)(b * N + n0 + tid)) * S);
            oa[0] = o0;
            oa[1] = o1;
        }
        if (role == 8 && tid < S) {
            float v = (tid < S - 1) ? sps[tid + 1] : 0.0f;
            if (tid == 0) v += sps[0];
            out_sp[b * S + tid] = v;
        }
        __syncthreads();
        const int c = tid & 63;          // float4 column 0..63
        const int r0 = (tid >> 6) * 32;  // row half 0 / 32
        const f32x4* base = reinterpret_cast<const f32x4*>(node + ((size_t)(b * N + n0)) * D) + c;
        f32x4 acc = {0.f, 0.f, 0.f, 0.f};
        f32x4 v[16];
        for (int ii = 0; ii < 32; ii += 16) {
            #pragma unroll
            for (int u = 0; u < 16; ++u) v[u] = base[(size_t)(r0 + ii + u) * (D / 4)];
            #pragma unroll
            for (int u = 0; u < 16; ++u) acc += kal[r0 + ii + u] * v[u];
        }
        if (tid >= 64) red[c] = acc;     // upper half publishes
        __syncthreads();
        if (tid < 64) {
            f32x4 s = acc + red[c];
            float* dst = kf + b * D + c * 4;
            atomicAdd(dst + 0, s.x);     // device-scope (m20): coherent for q-block
            atomicAdd(dst + 1, s.y);
            atomicAdd(dst + 2, s.z);
            atomicAdd(dst + 3, s.w);
        }
    }

    // ---- completion counter; last block of this b computes q[b] ----
    __syncthreads();                     // all lanes' atomics issued+drained
    if (tid == 0) {
        __threadfence();
        int ret = __hip_atomic_fetch_add(cnt + b, 1, __ATOMIC_ACQ_REL,
                                         __HIP_MEMORY_SCOPE_AGENT);
        lastFlag = (ret == 15);
    }
    __syncthreads();
    if (lastFlag) {
        __shared__ float kfl[D];
        for (int d = tid; d < D; d += 128)
            kfl[d] = __hip_atomic_load(kf + (size_t)b * D + d, __ATOMIC_ACQUIRE,
                                       __HIP_MEMORY_SCOPE_AGENT);
        __syncthreads();
        const float4* kf4 = reinterpret_cast<const float4*>(kfl);
        for (int d = tid; d < D; d += 128) {
            float acc = bias[d];
            const float4* wrow = reinterpret_cast<const float4*>(Wm + (size_t)d * D);
            #pragma unroll 8
            for (int k = 0; k < D / 4; ++k) {
                float4 w = wrow[k];
                float4 f = kf4[k];
                acc += w.x * f.x + w.y * f.y + w.z * f.z + w.w * f.w;
            }
            q[(size_t)b * D + d] = acc;
        }
    }
}

// ---------------------------------------------------------------------------
// K3: out_vm[b,n] = vm[b,n] + em[b,n] * dot(node[b,n,:], q[b,:])
// one wave per row (64 lanes x float4 = 256 floats); 32 rows per block.
// ---------------------------------------------------------------------------
__global__ void kD_logits(const float* __restrict__ node,
                          const float* __restrict__ em,
                          const float* __restrict__ q,
                          const float* __restrict__ vm,
                          float* __restrict__ out_vm) {
    const int row0 = blockIdx.x * 32;
    const int b = row0 / N;
    const int tid = threadIdx.x;
    const int wave = tid >> 6;
    const int lane = tid & 63;
    __shared__ float ql[D];
    if (tid < D) ql[tid] = q[b * D + tid];
    __syncthreads();
    const float4 q4 = reinterpret_cast<const float4*>(ql)[lane];
    const int wr0 = row0 + wave * 8;
    float emv = 0.f, vmv = 0.f;
    if (lane < 8) {
        emv = em[wr0 + lane];
        vmv = vm[wr0 + lane];
    }
    float4 v[8];
    #pragma unroll
    for (int r = 0; r < 8; ++r)
        v[r] = reinterpret_cast<const float4*>(node + (size_t)(wr0 + r) * D)[lane];
    float myS = 0.f;
    #pragma unroll
    for (int r = 0; r < 8; ++r) {
        float s = v[r].x * q4.x + v[r].y * q4.y + v[r].z * q4.z + v[r].w * q4.w;
        #pragma unroll
        for (int off = 32; off; off >>= 1) s += __shfl_xor(s, off);
        if (lane == r) myS = s;
    }
    if (lane < 8) {
        out_vm[wr0 + lane] = vmv + emv * myS;
    }
}

extern "C" void kernel_launch(void* const* d_in, const int* in_sizes, int n_in,
                              void* d_out, int out_size, void* d_ws, size_t ws_size,
                              hipStream_t stream) {
    const float* node = (const float*)d_in[0];
    // d_in[1] = query : unused by the reference computation
    const float* edge = (const float*)d_in[2];
    const float* att  = (const float*)d_in[3];
    const float* sp   = (const float*)d_in[4];
    const float* vm   = (const float*)d_in[5];
    const float* Wm   = (const float*)d_in[6];
    const float* bias = (const float*)d_in[7];

    float* out_att = (float*)d_out;                    // B*N*S
    float* out_sp  = out_att + (size_t)B * N * S;      // B*S
    float* out_vm  = out_sp + (size_t)B * S;           // B*N

    float* ws = (float*)d_ws;
    float* kf = ws;                          // B*D (atomic-accumulated -> zero)
    float* em = kf + (size_t)B * D;          // B*N (atomic-accumulated -> zero)
    int*   cnt = (int*)(em + (size_t)B * N); // B counters (-> zero)
    float* q  = (float*)(cnt + B);           // B*D

    // zero kf + em + cnt (contiguous)
    (void)hipMemsetAsync(kf, 0,
        (size_t)(B * D + B * N) * sizeof(float) + B * sizeof(int), stream);

    k1_fused<<<dim3(16, B), 128, 0, stream>>>(node, edge, att, sp, Wm, bias,
                                              out_att, out_sp, kf, em, q, cnt);
    kD_logits<<<(B * N) / 32, 256, 0, stream>>>(node, em, q, vm, out_vm);
}